// Round 4
// baseline (5385.644 us; speedup 1.0000x reference)
//
#include <hip/hip_runtime.h>
#include <hip/hip_bf16.h>

#define S_LEN 1024
#define E_DIM 512
#define INNER_D 1024
#define NHEAD 8
#define DHEAD 128

// ---------------- embedding: x = concat(x_enc, x_mark_enc) @ emb_W + emb_b ----------------
__global__ __launch_bounds__(128) void embed_kernel(
    const float* __restrict__ xe, const float* __restrict__ xm,
    const float* __restrict__ W, const float* __restrict__ bias,
    float* __restrict__ x)
{
  int row = blockIdx.x;  // b*S+s, 2048 rows
  int tid = threadIdx.x;
  __shared__ float in_s[25];
  if (tid < 21) in_s[tid] = xe[row * 21 + tid];
  else if (tid < 25) in_s[tid] = xm[row * 4 + tid - 21];
  __syncthreads();
#pragma unroll
  for (int rep = 0; rep < 4; rep++) {
    int e = tid + rep * 128;
    float acc = bias[e];
#pragma unroll
    for (int i = 0; i < 25; i++) acc += in_s[i] * W[i * E_DIM + e];
    x[(size_t)row * E_DIM + e] = acc;
  }
}

// ---------------- layernorm (weight only, eps=1e-5), E=512, block=256 ----------------
__global__ __launch_bounds__(256) void ln_kernel(
    const float* __restrict__ x, const float* __restrict__ w, float* __restrict__ out)
{
  int row = blockIdx.x, tid = threadIdx.x;
  const float* xr = x + (size_t)row * E_DIM;
  float2 v = *(const float2*)(xr + tid * 2);
  float s = v.x + v.y, q = v.x * v.x + v.y * v.y;
#pragma unroll
  for (int off = 32; off; off >>= 1) { s += __shfl_xor(s, off); q += __shfl_xor(q, off); }
  __shared__ float ssum[4], ssq[4];
  int wv = tid >> 6;
  if ((tid & 63) == 0) { ssum[wv] = s; ssq[wv] = q; }
  __syncthreads();
  s = ssum[0] + ssum[1] + ssum[2] + ssum[3];
  q = ssq[0] + ssq[1] + ssq[2] + ssq[3];
  float mu = s * (1.f / E_DIM);
  float var = q * (1.f / E_DIM) - mu * mu;
  float rs = rsqrtf(var + 1e-5f);
  int e = tid * 2;
  float2 o;
  o.x = (v.x - mu) * rs * w[e];
  o.y = (v.y - mu) * rs * w[e + 1];
  *(float2*)(out + (size_t)row * E_DIM + e) = o;
}

__global__ __launch_bounds__(256) void ln_final_kernel(
    const float* __restrict__ x, const float* __restrict__ w, float* __restrict__ out)
{
  int ridx = blockIdx.x;  // 0..191
  int b = ridx / 96, r = ridx % 96;
  int row = b * S_LEN + (S_LEN - 96) + r;
  int tid = threadIdx.x;
  const float* xr = x + (size_t)row * E_DIM;
  float2 v = *(const float2*)(xr + tid * 2);
  float s = v.x + v.y, q = v.x * v.x + v.y * v.y;
#pragma unroll
  for (int off = 32; off; off >>= 1) { s += __shfl_xor(s, off); q += __shfl_xor(q, off); }
  __shared__ float ssum[4], ssq[4];
  int wv = tid >> 6;
  if ((tid & 63) == 0) { ssum[wv] = s; ssq[wv] = q; }
  __syncthreads();
  s = ssum[0] + ssum[1] + ssum[2] + ssum[3];
  q = ssq[0] + ssq[1] + ssq[2] + ssq[3];
  float mu = s * (1.f / E_DIM);
  float var = q * (1.f / E_DIM) - mu * mu;
  float rs = rsqrtf(var + 1e-5f);
  int e = tid * 2;
  float2 o;
  o.x = (v.x - mu) * rs * w[e];
  o.y = (v.y - mu) * rs * w[e + 1];
  *(float2*)(out + (size_t)ridx * E_DIM + e) = o;
}

// ---------------- tiled GEMM: C[M,N] (+)= A[M,K] @ B[K,N], f32; optional column-split C ----------------
// grid = (N/64, M/64), block = 256. If C1 != nullptr, cols >= split_col land in C1 (rebased).
template <int ADD>
__global__ __launch_bounds__(256) void gemm_f32(
    const float* __restrict__ A, const float* __restrict__ Bw,
    float* __restrict__ C0, float* __restrict__ C1,
    int M, int N, int K, int lda, int split_col, int ldc)
{
  __shared__ float As[16][68];
  __shared__ float Bs[16][68];
  const int tid = threadIdx.x;
  const int tx = tid & 15, ty = tid >> 4;
  const int row0 = blockIdx.y * 64, col0 = blockIdx.x * 64;
  const int mA = tid >> 2;         // 0..63
  const int kA = (tid & 3) * 4;    // 0,4,8,12
  const int kB = tid >> 6;         // 0..3
  const int nB = tid & 63;
  float acc[4][4] = {};
  for (int k0 = 0; k0 < K; k0 += 16) {
    float4 a4 = *(const float4*)(A + (size_t)(row0 + mA) * lda + k0 + kA);
    As[kA + 0][mA] = a4.x; As[kA + 1][mA] = a4.y; As[kA + 2][mA] = a4.z; As[kA + 3][mA] = a4.w;
#pragma unroll
    for (int i = 0; i < 4; i++) {
      int kk = kB + i * 4;
      Bs[kk][nB] = Bw[(size_t)(k0 + kk) * N + col0 + nB];
    }
    __syncthreads();
#pragma unroll
    for (int k = 0; k < 16; k++) {
      float4 a = *(const float4*)&As[k][ty * 4];
      float4 b = *(const float4*)&Bs[k][tx * 4];
      acc[0][0] += a.x * b.x; acc[0][1] += a.x * b.y; acc[0][2] += a.x * b.z; acc[0][3] += a.x * b.w;
      acc[1][0] += a.y * b.x; acc[1][1] += a.y * b.y; acc[1][2] += a.y * b.z; acc[1][3] += a.y * b.w;
      acc[2][0] += a.z * b.x; acc[2][1] += a.z * b.y; acc[2][2] += a.z * b.z; acc[2][3] += a.z * b.w;
      acc[3][0] += a.w * b.x; acc[3][1] += a.w * b.y; acc[3][2] += a.w * b.z; acc[3][3] += a.w * b.w;
    }
    __syncthreads();
  }
  float* Cb = C0;
  int ccol = col0;
  if (C1 && col0 >= split_col) { Cb = C1; ccol = col0 - split_col; }
#pragma unroll
  for (int i = 0; i < 4; i++) {
    float* cp = Cb + (size_t)(row0 + ty * 4 + i) * ldc + ccol + tx * 4;
    if (ADD) {
      cp[0] += acc[i][0]; cp[1] += acc[i][1]; cp[2] += acc[i][2]; cp[3] += acc[i][3];
    } else {
      float4 st; st.x = acc[i][0]; st.y = acc[i][1]; st.z = acc[i][2]; st.w = acc[i][3];
      *(float4*)cp = st;
    }
  }
}

// ---------------- causal depthwise conv (K=4) + bias + SiLU ----------------
__global__ __launch_bounds__(256) void conv_silu_kernel(
    const float* __restrict__ xm, const float* __restrict__ cw, const float* __restrict__ cb,
    float* __restrict__ xc)
{
  int idx = blockIdx.x * 256 + threadIdx.x;  // B*S*256
  int g = idx & 255;
  int row = idx >> 8;
  int s = row & (S_LEN - 1);
  int c0 = g * 4;
  const float* base = xm + (size_t)row * INNER_D + c0;
  float4 acc = {0.f, 0.f, 0.f, 0.f};
#pragma unroll
  for (int kk = 0; kk < 4; kk++) {
    int ts = s - 3 + kk;
    if (ts >= 0) {
      float4 xv = *(const float4*)(base + (ptrdiff_t)(kk - 3) * INNER_D);
      acc.x += xv.x * cw[(c0 + 0) * 4 + kk];
      acc.y += xv.y * cw[(c0 + 1) * 4 + kk];
      acc.z += xv.z * cw[(c0 + 2) * 4 + kk];
      acc.w += xv.w * cw[(c0 + 3) * 4 + kk];
    }
  }
  acc.x += cb[c0 + 0]; acc.y += cb[c0 + 1];
  acc.z += cb[c0 + 2]; acc.w += cb[c0 + 3];
  acc.x = acc.x / (1.f + __expf(-acc.x));
  acc.y = acc.y / (1.f + __expf(-acc.y));
  acc.z = acc.z / (1.f + __expf(-acc.z));
  acc.w = acc.w / (1.f + __expf(-acc.w));
  *(float4*)(xc + (size_t)row * INNER_D + c0) = acc;
}

// ---------------- headwise 4x4 projections: q,k from xc; v from xm ----------------
__global__ __launch_bounds__(256) void qkv_headwise_kernel(
    const float* __restrict__ xc, const float* __restrict__ xm,
    const float* __restrict__ qw, const float* __restrict__ kw, const float* __restrict__ vw,
    float* __restrict__ q, float* __restrict__ k, float* __restrict__ v)
{
  int idx = blockIdx.x * 256 + threadIdx.x;
  int g = idx & 255;
  size_t row = idx >> 8;
  float4 xc4 = *(const float4*)(xc + row * INNER_D + g * 4);
  float4 xm4 = *(const float4*)(xm + row * INNER_D + g * 4);
  const float* qg = qw + g * 16;
  const float* kg = kw + g * 16;
  const float* vg = vw + g * 16;
  float xcv[4] = {xc4.x, xc4.y, xc4.z, xc4.w};
  float xmv[4] = {xm4.x, xm4.y, xm4.z, xm4.w};
  float qo[4], ko[4], vo[4];
#pragma unroll
  for (int o = 0; o < 4; o++) {
    float aq = 0.f, ak = 0.f, av = 0.f;
#pragma unroll
    for (int d = 0; d < 4; d++) {
      aq += xcv[d] * qg[o * 4 + d];
      ak += xcv[d] * kg[o * 4 + d];
      av += xmv[d] * vg[o * 4 + d];
    }
    qo[o] = aq; ko[o] = ak; vo[o] = av;
  }
  float4 qs = {qo[0], qo[1], qo[2], qo[3]};
  float4 ks = {ko[0], ko[1], ko[2], ko[3]};
  float4 vs = {vo[0], vo[1], vo[2], vo[3]};
  *(float4*)(q + row * INNER_D + g * 4) = qs;
  *(float4*)(k + row * INNER_D + g * 4) = ks;
  *(float4*)(v + row * INNER_D + g * 4) = vs;
}

// ---------------- gate GEMVs: ig/fg[b,n,s] ----------------
__global__ __launch_bounds__(256) void gates_kernel(
    const float* __restrict__ q, const float* __restrict__ k, const float* __restrict__ v,
    const float* __restrict__ igW, const float* __restrict__ igb,
    const float* __restrict__ fgW, const float* __restrict__ fgb,
    float* __restrict__ ig, float* __restrict__ fg)
{
  int row = blockIdx.x;
  int b = row >> 10, s = row & (S_LEN - 1);
  int tid = threadIdx.x;
  float ia[8] = {}, fa[8] = {};
#pragma unroll
  for (int i = 0; i < 12; i++) {
    int j = tid + i * 256;
    float xv;
    if (j < 1024) xv = q[(size_t)row * INNER_D + j];
    else if (j < 2048) xv = k[(size_t)row * INNER_D + j - 1024];
    else xv = v[(size_t)row * INNER_D + j - 2048];
    float4 wi0 = *(const float4*)(igW + (size_t)j * 8);
    float4 wi1 = *(const float4*)(igW + (size_t)j * 8 + 4);
    float4 wf0 = *(const float4*)(fgW + (size_t)j * 8);
    float4 wf1 = *(const float4*)(fgW + (size_t)j * 8 + 4);
    ia[0] += xv * wi0.x; ia[1] += xv * wi0.y; ia[2] += xv * wi0.z; ia[3] += xv * wi0.w;
    ia[4] += xv * wi1.x; ia[5] += xv * wi1.y; ia[6] += xv * wi1.z; ia[7] += xv * wi1.w;
    fa[0] += xv * wf0.x; fa[1] += xv * wf0.y; fa[2] += xv * wf0.z; fa[3] += xv * wf0.w;
    fa[4] += xv * wf1.x; fa[5] += xv * wf1.y; fa[6] += xv * wf1.z; fa[7] += xv * wf1.w;
  }
#pragma unroll
  for (int off = 32; off; off >>= 1) {
#pragma unroll
    for (int n = 0; n < 8; n++) {
      ia[n] += __shfl_xor(ia[n], off);
      fa[n] += __shfl_xor(fa[n], off);
    }
  }
  __shared__ float red[2][4][8];
  int wv = tid >> 6;
  if ((tid & 63) == 0) {
#pragma unroll
    for (int n = 0; n < 8; n++) { red[0][wv][n] = ia[n]; red[1][wv][n] = fa[n]; }
  }
  __syncthreads();
  if (tid < 8) {
    float si = red[0][0][tid] + red[0][1][tid] + red[0][2][tid] + red[0][3][tid];
    float sf = red[1][0][tid] + red[1][1][tid] + red[1][2][tid] + red[1][3][tid];
    size_t o = ((size_t)(b * NHEAD + tid) << 10) + s;
    ig[o] = si + igb[tid];
    fg[o] = sf + fgb[tid];
  }
}

// ---------------- per-(b,h) scans: cs=cumsum(logsigmoid(fg)); a=ig-cs; rm=runmax(a); enm=exp(-(cs+rm))
__global__ __launch_bounds__(1024) void scan_kernel(
    const float* __restrict__ ig, const float* __restrict__ fg,
    float* __restrict__ a, float* __restrict__ rm, float* __restrict__ enm)
{
  int bh = blockIdx.x;
  int t = threadIdx.x;
  __shared__ float buf[1024];
  size_t o = ((size_t)bh << 10) + t;
  float f = fg[o];
  float lf = (f >= 0.f) ? -log1pf(__expf(-f)) : f - log1pf(__expf(f));
  buf[t] = lf;
  __syncthreads();
  float run = lf;
  for (int off = 1; off < 1024; off <<= 1) {
    float add = (t >= off) ? buf[t - off] : 0.f;
    __syncthreads();
    run += add;
    buf[t] = run;
    __syncthreads();
  }
  float cs = run;
  float av = ig[o] - cs;
  a[o] = av;
  buf[t] = av;
  __syncthreads();
  float rmx = av;
  for (int off = 1; off < 1024; off <<= 1) {
    float m = (t >= off) ? buf[t - off] : -3.4e38f;
    __syncthreads();
    rmx = fmaxf(rmx, m);
    buf[t] = rmx;
    __syncthreads();
  }
  rm[o] = rmx;
  enm[o] = __expf(-(cs + rmx));
}

// ---------------- attention: wave per 4 rows of one (b,h); fused epilogue ----------------
__global__ __launch_bounds__(256) void attn_kernel(
    const float* __restrict__ q, const float* __restrict__ k, const float* __restrict__ v,
    const float* __restrict__ a_arr, const float* __restrict__ rm_arr, const float* __restrict__ enm_arr,
    const float* __restrict__ xc, const float* __restrict__ z,
    const float* __restrict__ skip, const float* __restrict__ onw,
    float* __restrict__ hs)
{
  int wave = threadIdx.x >> 6, lane = threadIdx.x & 63;
  int tile = blockIdx.x & 63;
  int bh = blockIdx.x >> 6;
  int b = bh >> 3, h = bh & 7;
  int s0 = tile * 16 + wave * 4;
  int d0 = lane * 2, c0 = h * DHEAD + d0;
  size_t rowbase = (size_t)b * S_LEN;
  float2 qr[4];
  float rmv[4];
#pragma unroll
  for (int r = 0; r < 4; r++) {
    int s = s0 + r;
    qr[r] = *(const float2*)(q + (rowbase + s) * INNER_D + c0);
    rmv[r] = rm_arr[(size_t)bh * S_LEN + s];
  }
  float2 acc[4] = {{0.f,0.f},{0.f,0.f},{0.f,0.f},{0.f,0.f}};
  float sC[4] = {0.f, 0.f, 0.f, 0.f};
  const float* kp = k + rowbase * INNER_D + c0;
  const float* vp = v + rowbase * INNER_D + c0;
  const float* ap = a_arr + (size_t)bh * S_LEN;
  const float scale = 0.08838834764831845f;  // 1/sqrt(128)
  for (int t = 0; t <= s0 + 3; t++) {
    float2 k2 = *(const float2*)(kp + (size_t)t * INNER_D);
    float2 v2 = *(const float2*)(vp + (size_t)t * INNER_D);
    float at = ap[t];
    float p0 = qr[0].x * k2.x + qr[0].y * k2.y;
    float p1 = qr[1].x * k2.x + qr[1].y * k2.y;
    float p2 = qr[2].x * k2.x + qr[2].y * k2.y;
    float p3 = qr[3].x * k2.x + qr[3].y * k2.y;
#pragma unroll
    for (int off = 32; off; off >>= 1) {
      p0 += __shfl_xor(p0, off);
      p1 += __shfl_xor(p1, off);
      p2 += __shfl_xor(p2, off);
      p3 += __shfl_xor(p3, off);
    }
    float w0 = p0 * scale * __expf(at - rmv[0]); if (t > s0 + 0) w0 = 0.f;
    float w1 = p1 * scale * __expf(at - rmv[1]); if (t > s0 + 1) w1 = 0.f;
    float w2 = p2 * scale * __expf(at - rmv[2]); if (t > s0 + 2) w2 = 0.f;
    float w3 = p3 * scale * __expf(at - rmv[3]);
    sC[0] += w0; acc[0].x += w0 * v2.x; acc[0].y += w0 * v2.y;
    sC[1] += w1; acc[1].x += w1 * v2.x; acc[1].y += w1 * v2.y;
    sC[2] += w2; acc[2].x += w2 * v2.x; acc[2].y += w2 * v2.y;
    sC[3] += w3; acc[3].x += w3 * v2.x; acc[3].y += w3 * v2.y;
  }
  float skx = skip[c0], sky = skip[c0 + 1];
  float owx = onw[c0], owy = onw[c0 + 1];
#pragma unroll
  for (int r = 0; r < 4; r++) {
    int s = s0 + r;
    float norm = fmaxf(fabsf(sC[r]), enm_arr[(size_t)bh * S_LEN + s]);
    float inv = 1.f / (norm + 1e-6f);
    float hx = acc[r].x * inv, hy = acc[r].y * inv;
    float sm = hx + hy, sq = hx * hx + hy * hy;
#pragma unroll
    for (int off = 32; off; off >>= 1) { sm += __shfl_xor(sm, off); sq += __shfl_xor(sq, off); }
    float mu = sm * (1.f / DHEAD);
    float var = sq * (1.f / DHEAD) - mu * mu;
    float rs = rsqrtf(var + 1e-5f);
    float hnx = (hx - mu) * rs * owx;
    float hny = (hy - mu) * rs * owy;
    float2 xc2 = *(const float2*)(xc + (rowbase + s) * INNER_D + c0);
    float2 z2 = *(const float2*)(z + (rowbase + s) * INNER_D + c0);
    float o1 = (hnx + skx * xc2.x) * (z2.x / (1.f + __expf(-z2.x)));
    float o2 = (hny + sky * xc2.y) * (z2.y / (1.f + __expf(-z2.y)));
    float2 o; o.x = o1; o.y = o2;
    *(float2*)(hs + (rowbase + s) * INNER_D + c0) = o;
  }
}

// ---------------- head: out[192,21] = ln96 @ head_W + head_b, store f32 ----------------
__global__ __launch_bounds__(64) void head_kernel(
    const float* __restrict__ ln96, const float* __restrict__ hW, const float* __restrict__ hb,
    float* __restrict__ out)
{
  int row = blockIdx.x;  // 0..191
  int n = threadIdx.x;
  if (n >= 21) return;
  float acc = hb[n];
  const float* xr = ln96 + (size_t)row * E_DIM;
  for (int kk = 0; kk < E_DIM; kk++) acc += xr[kk] * hW[kk * 21 + n];
  out[row * 21 + n] = acc;
}

extern "C" void kernel_launch(void* const* d_in, const int* in_sizes, int n_in,
                              void* d_out, int out_size, void* d_ws, size_t ws_size,
                              hipStream_t stream)
{
  // All inputs are float32 (reference is pure f32); output is float32.
  const float* x_enc   = (const float*)d_in[0];
  const float* x_mark  = (const float*)d_in[1];
  const float* emb_W   = (const float*)d_in[4];
  const float* emb_b   = (const float*)d_in[5];
  const float* ln_w    = (const float*)d_in[6];
  const float* up_W    = (const float*)d_in[7];
  const float* conv_W  = (const float*)d_in[8];
  const float* conv_b  = (const float*)d_in[9];
  const float* q_W     = (const float*)d_in[10];
  const float* k_W     = (const float*)d_in[11];
  const float* v_W     = (const float*)d_in[12];
  const float* ig_W    = (const float*)d_in[13];
  const float* ig_b    = (const float*)d_in[14];
  const float* fg_W    = (const float*)d_in[15];
  const float* fg_b    = (const float*)d_in[16];
  const float* skip_w  = (const float*)d_in[17];
  const float* onorm_w = (const float*)d_in[18];
  const float* down_W  = (const float*)d_in[19];
  const float* post_ln = (const float*)d_in[20];
  const float* head_W  = (const float*)d_in[21];
  const float* head_b  = (const float*)d_in[22];

  float* p = (float*)d_ws;
  float* x    = p; p += 1048576;   // 2048*512
  float* xn   = p; p += 1048576;
  float* xm   = p; p += 2097152;   // 2048*1024 (reused as hs after qkv)
  float* z    = p; p += 2097152;
  float* xc   = p; p += 2097152;
  float* qb   = p; p += 2097152;
  float* kb   = p; p += 2097152;
  float* vb   = p; p += 2097152;
  float* igb_ = p; p += 16384;     // 16*1024
  float* fgb_ = p; p += 16384;
  float* ab   = p; p += 16384;
  float* rmb  = p; p += 16384;
  float* enmb = p; p += 16384;
  float* ln96 = p; p += 98304;     // 192*512
  float* hsb  = xm;  // alias: xm dead after qkv_headwise

  embed_kernel<<<2048, 128, 0, stream>>>(x_enc, x_mark, emb_W, emb_b, x);

  for (int L = 0; L < 4; L++) {
    ln_kernel<<<2048, 256, 0, stream>>>(x, ln_w + L * 512, xn);
    gemm_f32<0><<<dim3(32, 32), 256, 0, stream>>>(
        xn, up_W + (size_t)L * 512 * 2048, xm, z, 2048, 2048, 512, 512, 1024, 1024);
    conv_silu_kernel<<<2048, 256, 0, stream>>>(xm, conv_W + L * 4096, conv_b + L * 1024, xc);
    qkv_headwise_kernel<<<2048, 256, 0, stream>>>(
        xc, xm, q_W + L * 4096, k_W + L * 4096, v_W + L * 4096, qb, kb, vb);
    gates_kernel<<<2048, 256, 0, stream>>>(
        qb, kb, vb, ig_W + L * 24576, ig_b + L * 8, fg_W + L * 24576, fg_b + L * 8, igb_, fgb_);
    scan_kernel<<<16, 1024, 0, stream>>>(igb_, fgb_, ab, rmb, enmb);
    attn_kernel<<<1024, 256, 0, stream>>>(
        qb, kb, vb, ab, rmb, enmb, xc, z, skip_w + L * 1024, onorm_w + L * 1024, hsb);
    gemm_f32<1><<<dim3(8, 32), 256, 0, stream>>>(
        hsb, down_W + (size_t)L * 1024 * 512, x, nullptr, 2048, 512, 1024, 1024, 1 << 30, 512);
  }

  ln_final_kernel<<<192, 256, 0, stream>>>(x, post_ln, ln96);
  head_kernel<<<192, 64, 0, stream>>>(ln96, head_W, head_b, (float*)d_out);
}

// Round 5
// 1636.841 us; speedup vs baseline: 3.2903x; 3.2903x over previous
//
#include <hip/hip_runtime.h>
#include <hip/hip_bf16.h>

#define S_LEN 1024
#define E_DIM 512
#define INNER_D 1024
#define NHEAD 8
#define DHEAD 128

// ---------------- embedding: x = concat(x_enc, x_mark_enc) @ emb_W + emb_b ----------------
__global__ __launch_bounds__(128) void embed_kernel(
    const float* __restrict__ xe, const float* __restrict__ xm,
    const float* __restrict__ W, const float* __restrict__ bias,
    float* __restrict__ x)
{
  int row = blockIdx.x;  // b*S+s, 2048 rows
  int tid = threadIdx.x;
  __shared__ float in_s[25];
  if (tid < 21) in_s[tid] = xe[row * 21 + tid];
  else if (tid < 25) in_s[tid] = xm[row * 4 + tid - 21];
  __syncthreads();
#pragma unroll
  for (int rep = 0; rep < 4; rep++) {
    int e = tid + rep * 128;
    float acc = bias[e];
#pragma unroll
    for (int i = 0; i < 25; i++) acc += in_s[i] * W[i * E_DIM + e];
    x[(size_t)row * E_DIM + e] = acc;
  }
}

// ---------------- layernorm (weight only, eps=1e-5), E=512, block=256 ----------------
__global__ __launch_bounds__(256) void ln_kernel(
    const float* __restrict__ x, const float* __restrict__ w, float* __restrict__ out)
{
  int row = blockIdx.x, tid = threadIdx.x;
  const float* xr = x + (size_t)row * E_DIM;
  float2 v = *(const float2*)(xr + tid * 2);
  float s = v.x + v.y, q = v.x * v.x + v.y * v.y;
#pragma unroll
  for (int off = 32; off; off >>= 1) { s += __shfl_xor(s, off); q += __shfl_xor(q, off); }
  __shared__ float ssum[4], ssq[4];
  int wv = tid >> 6;
  if ((tid & 63) == 0) { ssum[wv] = s; ssq[wv] = q; }
  __syncthreads();
  s = ssum[0] + ssum[1] + ssum[2] + ssum[3];
  q = ssq[0] + ssq[1] + ssq[2] + ssq[3];
  float mu = s * (1.f / E_DIM);
  float var = q * (1.f / E_DIM) - mu * mu;
  float rs = rsqrtf(var + 1e-5f);
  int e = tid * 2;
  float2 o;
  o.x = (v.x - mu) * rs * w[e];
  o.y = (v.y - mu) * rs * w[e + 1];
  *(float2*)(out + (size_t)row * E_DIM + e) = o;
}

__global__ __launch_bounds__(256) void ln_final_kernel(
    const float* __restrict__ x, const float* __restrict__ w, float* __restrict__ out)
{
  int ridx = blockIdx.x;  // 0..191
  int b = ridx / 96, r = ridx % 96;
  int row = b * S_LEN + (S_LEN - 96) + r;
  int tid = threadIdx.x;
  const float* xr = x + (size_t)row * E_DIM;
  float2 v = *(const float2*)(xr + tid * 2);
  float s = v.x + v.y, q = v.x * v.x + v.y * v.y;
#pragma unroll
  for (int off = 32; off; off >>= 1) { s += __shfl_xor(s, off); q += __shfl_xor(q, off); }
  __shared__ float ssum[4], ssq[4];
  int wv = tid >> 6;
  if ((tid & 63) == 0) { ssum[wv] = s; ssq[wv] = q; }
  __syncthreads();
  s = ssum[0] + ssum[1] + ssum[2] + ssum[3];
  q = ssq[0] + ssq[1] + ssq[2] + ssq[3];
  float mu = s * (1.f / E_DIM);
  float var = q * (1.f / E_DIM) - mu * mu;
  float rs = rsqrtf(var + 1e-5f);
  int e = tid * 2;
  float2 o;
  o.x = (v.x - mu) * rs * w[e];
  o.y = (v.y - mu) * rs * w[e + 1];
  *(float2*)(out + (size_t)ridx * E_DIM + e) = o;
}

// ---------------- tiled GEMM: C[M,N] (+)= A[M,K] @ B[K,N], f32; optional column-split C ----------------
template <int ADD>
__global__ __launch_bounds__(256) void gemm_f32(
    const float* __restrict__ A, const float* __restrict__ Bw,
    float* __restrict__ C0, float* __restrict__ C1,
    int M, int N, int K, int lda, int split_col, int ldc)
{
  __shared__ float As[16][68];
  __shared__ float Bs[16][68];
  const int tid = threadIdx.x;
  const int tx = tid & 15, ty = tid >> 4;
  const int row0 = blockIdx.y * 64, col0 = blockIdx.x * 64;
  const int mA = tid >> 2;         // 0..63
  const int kA = (tid & 3) * 4;    // 0,4,8,12
  const int kB = tid >> 6;         // 0..3
  const int nB = tid & 63;
  float acc[4][4] = {};
  for (int k0 = 0; k0 < K; k0 += 16) {
    float4 a4 = *(const float4*)(A + (size_t)(row0 + mA) * lda + k0 + kA);
    As[kA + 0][mA] = a4.x; As[kA + 1][mA] = a4.y; As[kA + 2][mA] = a4.z; As[kA + 3][mA] = a4.w;
#pragma unroll
    for (int i = 0; i < 4; i++) {
      int kk = kB + i * 4;
      Bs[kk][nB] = Bw[(size_t)(k0 + kk) * N + col0 + nB];
    }
    __syncthreads();
#pragma unroll
    for (int k = 0; k < 16; k++) {
      float4 a = *(const float4*)&As[k][ty * 4];
      float4 b = *(const float4*)&Bs[k][tx * 4];
      acc[0][0] += a.x * b.x; acc[0][1] += a.x * b.y; acc[0][2] += a.x * b.z; acc[0][3] += a.x * b.w;
      acc[1][0] += a.y * b.x; acc[1][1] += a.y * b.y; acc[1][2] += a.y * b.z; acc[1][3] += a.y * b.w;
      acc[2][0] += a.z * b.x; acc[2][1] += a.z * b.y; acc[2][2] += a.z * b.z; acc[2][3] += a.z * b.w;
      acc[3][0] += a.w * b.x; acc[3][1] += a.w * b.y; acc[3][2] += a.w * b.z; acc[3][3] += a.w * b.w;
    }
    __syncthreads();
  }
  float* Cb = C0;
  int ccol = col0;
  if (C1 && col0 >= split_col) { Cb = C1; ccol = col0 - split_col; }
#pragma unroll
  for (int i = 0; i < 4; i++) {
    float* cp = Cb + (size_t)(row0 + ty * 4 + i) * ldc + ccol + tx * 4;
    if (ADD) {
      cp[0] += acc[i][0]; cp[1] += acc[i][1]; cp[2] += acc[i][2]; cp[3] += acc[i][3];
    } else {
      float4 st; st.x = acc[i][0]; st.y = acc[i][1]; st.z = acc[i][2]; st.w = acc[i][3];
      *(float4*)cp = st;
    }
  }
}

// ---------------- causal depthwise conv (K=4) + bias + SiLU ----------------
__global__ __launch_bounds__(256) void conv_silu_kernel(
    const float* __restrict__ xm, const float* __restrict__ cw, const float* __restrict__ cb,
    float* __restrict__ xc)
{
  int idx = blockIdx.x * 256 + threadIdx.x;  // B*S*256
  int g = idx & 255;
  int row = idx >> 8;
  int s = row & (S_LEN - 1);
  int c0 = g * 4;
  const float* base = xm + (size_t)row * INNER_D + c0;
  float4 acc = {0.f, 0.f, 0.f, 0.f};
#pragma unroll
  for (int kk = 0; kk < 4; kk++) {
    int ts = s - 3 + kk;
    if (ts >= 0) {
      float4 xv = *(const float4*)(base + (ptrdiff_t)(kk - 3) * INNER_D);
      acc.x += xv.x * cw[(c0 + 0) * 4 + kk];
      acc.y += xv.y * cw[(c0 + 1) * 4 + kk];
      acc.z += xv.z * cw[(c0 + 2) * 4 + kk];
      acc.w += xv.w * cw[(c0 + 3) * 4 + kk];
    }
  }
  acc.x += cb[c0 + 0]; acc.y += cb[c0 + 1];
  acc.z += cb[c0 + 2]; acc.w += cb[c0 + 3];
  acc.x = acc.x / (1.f + __expf(-acc.x));
  acc.y = acc.y / (1.f + __expf(-acc.y));
  acc.z = acc.z / (1.f + __expf(-acc.z));
  acc.w = acc.w / (1.f + __expf(-acc.w));
  *(float4*)(xc + (size_t)row * INNER_D + c0) = acc;
}

// ---------------- headwise 4x4 projections: q,k from xc; v from xm ----------------
__global__ __launch_bounds__(256) void qkv_headwise_kernel(
    const float* __restrict__ xc, const float* __restrict__ xm,
    const float* __restrict__ qw, const float* __restrict__ kw, const float* __restrict__ vw,
    float* __restrict__ q, float* __restrict__ k, float* __restrict__ v)
{
  int idx = blockIdx.x * 256 + threadIdx.x;
  int g = idx & 255;
  size_t row = idx >> 8;
  float4 xc4 = *(const float4*)(xc + row * INNER_D + g * 4);
  float4 xm4 = *(const float4*)(xm + row * INNER_D + g * 4);
  const float* qg = qw + g * 16;
  const float* kg = kw + g * 16;
  const float* vg = vw + g * 16;
  float xcv[4] = {xc4.x, xc4.y, xc4.z, xc4.w};
  float xmv[4] = {xm4.x, xm4.y, xm4.z, xm4.w};
  float qo[4], ko[4], vo[4];
#pragma unroll
  for (int o = 0; o < 4; o++) {
    float aq = 0.f, ak = 0.f, av = 0.f;
#pragma unroll
    for (int d = 0; d < 4; d++) {
      aq += xcv[d] * qg[o * 4 + d];
      ak += xcv[d] * kg[o * 4 + d];
      av += xmv[d] * vg[o * 4 + d];
    }
    qo[o] = aq; ko[o] = ak; vo[o] = av;
  }
  float4 qs = {qo[0], qo[1], qo[2], qo[3]};
  float4 ks = {ko[0], ko[1], ko[2], ko[3]};
  float4 vs = {vo[0], vo[1], vo[2], vo[3]};
  *(float4*)(q + row * INNER_D + g * 4) = qs;
  *(float4*)(k + row * INNER_D + g * 4) = ks;
  *(float4*)(v + row * INNER_D + g * 4) = vs;
}

// ---------------- gate GEMVs: ig/fg[b,n,s] ----------------
__global__ __launch_bounds__(256) void gates_kernel(
    const float* __restrict__ q, const float* __restrict__ k, const float* __restrict__ v,
    const float* __restrict__ igW, const float* __restrict__ igb,
    const float* __restrict__ fgW, const float* __restrict__ fgb,
    float* __restrict__ ig, float* __restrict__ fg)
{
  int row = blockIdx.x;
  int b = row >> 10, s = row & (S_LEN - 1);
  int tid = threadIdx.x;
  float ia[8] = {}, fa[8] = {};
#pragma unroll
  for (int i = 0; i < 12; i++) {
    int j = tid + i * 256;
    float xv;
    if (j < 1024) xv = q[(size_t)row * INNER_D + j];
    else if (j < 2048) xv = k[(size_t)row * INNER_D + j - 1024];
    else xv = v[(size_t)row * INNER_D + j - 2048];
    float4 wi0 = *(const float4*)(igW + (size_t)j * 8);
    float4 wi1 = *(const float4*)(igW + (size_t)j * 8 + 4);
    float4 wf0 = *(const float4*)(fgW + (size_t)j * 8);
    float4 wf1 = *(const float4*)(fgW + (size_t)j * 8 + 4);
    ia[0] += xv * wi0.x; ia[1] += xv * wi0.y; ia[2] += xv * wi0.z; ia[3] += xv * wi0.w;
    ia[4] += xv * wi1.x; ia[5] += xv * wi1.y; ia[6] += xv * wi1.z; ia[7] += xv * wi1.w;
    fa[0] += xv * wf0.x; fa[1] += xv * wf0.y; fa[2] += xv * wf0.z; fa[3] += xv * wf0.w;
    fa[4] += xv * wf1.x; fa[5] += xv * wf1.y; fa[6] += xv * wf1.z; fa[7] += xv * wf1.w;
  }
#pragma unroll
  for (int off = 32; off; off >>= 1) {
#pragma unroll
    for (int n = 0; n < 8; n++) {
      ia[n] += __shfl_xor(ia[n], off);
      fa[n] += __shfl_xor(fa[n], off);
    }
  }
  __shared__ float red[2][4][8];
  int wv = tid >> 6;
  if ((tid & 63) == 0) {
#pragma unroll
    for (int n = 0; n < 8; n++) { red[0][wv][n] = ia[n]; red[1][wv][n] = fa[n]; }
  }
  __syncthreads();
  if (tid < 8) {
    float si = red[0][0][tid] + red[0][1][tid] + red[0][2][tid] + red[0][3][tid];
    float sf = red[1][0][tid] + red[1][1][tid] + red[1][2][tid] + red[1][3][tid];
    size_t o = ((size_t)(b * NHEAD + tid) << 10) + s;
    ig[o] = si + igb[tid];
    fg[o] = sf + fgb[tid];
  }
}

// ---------------- per-(b,h) scans ----------------
__global__ __launch_bounds__(1024) void scan_kernel(
    const float* __restrict__ ig, const float* __restrict__ fg,
    float* __restrict__ a, float* __restrict__ rm, float* __restrict__ enm)
{
  int bh = blockIdx.x;
  int t = threadIdx.x;
  __shared__ float buf[1024];
  size_t o = ((size_t)bh << 10) + t;
  float f = fg[o];
  float lf = (f >= 0.f) ? -log1pf(__expf(-f)) : f - log1pf(__expf(f));
  buf[t] = lf;
  __syncthreads();
  float run = lf;
  for (int off = 1; off < 1024; off <<= 1) {
    float add = (t >= off) ? buf[t - off] : 0.f;
    __syncthreads();
    run += add;
    buf[t] = run;
    __syncthreads();
  }
  float cs = run;
  float av = ig[o] - cs;
  a[o] = av;
  buf[t] = av;
  __syncthreads();
  float rmx = av;
  for (int off = 1; off < 1024; off <<= 1) {
    float m = (t >= off) ? buf[t - off] : -3.4e38f;
    __syncthreads();
    rmx = fmaxf(rmx, m);
    buf[t] = rmx;
    __syncthreads();
  }
  rm[o] = rmx;
  enm[o] = __expf(-(cs + rmx));
}

// ---------------- tiled attention: block = (q-tile of 64 rows, bh); two-phase GEMM ----------------
// phase A: 64x64 scores = Q(64x128) . K^T(128x64); w = p*scale*exp(a[t]-rm[s]), causal mask
// phase B: H(64x128) += w(64x64) @ V(64x128). Fused norm/LN/skip/SiLU epilogue.
__global__ __launch_bounds__(256) void attn_tile_kernel(
    const float* __restrict__ q, const float* __restrict__ k, const float* __restrict__ v,
    const float* __restrict__ a_arr, const float* __restrict__ rm_arr, const float* __restrict__ enm_arr,
    const float* __restrict__ xc, const float* __restrict__ z,
    const float* __restrict__ skip, const float* __restrict__ onw,
    float* __restrict__ hs)
{
  const int qt = blockIdx.x;    // 0..15 (64-row q tiles)
  const int bh = blockIdx.y;    // 0..15
  const int b = bh >> 3, h = bh & 7;
  const int s0 = qt * 64;
  const int tid = threadIdx.x;
  const int tx = tid & 15, ty = tid >> 4;
  const size_t rowbase = (size_t)b * S_LEN;
  const int c0 = h * DHEAD;

  __shared__ float Qs[64 * 132];   // [row][d], pad 4
  __shared__ float KsW[64 * 132];  // K tile [col][d]; reused as w[64][68] after phase A
  __shared__ float Vs[64 * 132];   // [col][d]
  __shared__ float as_[64];
  __shared__ float invn[64];
  __shared__ float mu_s[64];
  __shared__ float rs_s[64];

  // stage Q tile (coalesced): 2048 float4, 8 per thread
#pragma unroll
  for (int rep = 0; rep < 8; rep++) {
    int idx = rep * 256 + tid;
    int r = idx >> 5, f4 = idx & 31;
    *(float4*)&Qs[r * 132 + f4 * 4] =
        *(const float4*)(q + (rowbase + s0 + r) * INNER_D + c0 + f4 * 4);
  }
  float rmv[4];
#pragma unroll
  for (int i = 0; i < 4; i++) rmv[i] = rm_arr[(size_t)bh * S_LEN + s0 + ty * 4 + i];

  float accH[4][8] = {};
  float sc_part[4] = {0.f, 0.f, 0.f, 0.f};
  const float scale = 0.08838834764831845f;  // 1/sqrt(128)

  for (int kt = 0; kt <= qt; kt++) {
    const int t0 = kt * 64;
    __syncthreads();  // previous phase B / Q-stage done before overwriting K/V
#pragma unroll
    for (int rep = 0; rep < 8; rep++) {
      int idx = rep * 256 + tid;
      int r = idx >> 5, f4 = idx & 31;
      *(float4*)&KsW[r * 132 + f4 * 4] =
          *(const float4*)(k + (rowbase + t0 + r) * INNER_D + c0 + f4 * 4);
      *(float4*)&Vs[r * 132 + f4 * 4] =
          *(const float4*)(v + (rowbase + t0 + r) * INNER_D + c0 + f4 * 4);
    }
    if (tid < 64) as_[tid] = a_arr[(size_t)bh * S_LEN + t0 + tid];
    __syncthreads();

    // phase A: p[i][j] = Q[s0+ty*4+i] . K[t0+tx*4+j]
    float p[4][4] = {};
    for (int d4 = 0; d4 < 32; d4++) {
      int d = d4 * 4;
      float4 qv0 = *(const float4*)&Qs[(ty * 4 + 0) * 132 + d];
      float4 qv1 = *(const float4*)&Qs[(ty * 4 + 1) * 132 + d];
      float4 qv2 = *(const float4*)&Qs[(ty * 4 + 2) * 132 + d];
      float4 qv3 = *(const float4*)&Qs[(ty * 4 + 3) * 132 + d];
      float4 kv0 = *(const float4*)&KsW[(tx * 4 + 0) * 132 + d];
      float4 kv1 = *(const float4*)&KsW[(tx * 4 + 1) * 132 + d];
      float4 kv2 = *(const float4*)&KsW[(tx * 4 + 2) * 132 + d];
      float4 kv3 = *(const float4*)&KsW[(tx * 4 + 3) * 132 + d];
      float4 qv[4] = {qv0, qv1, qv2, qv3};
      float4 kv[4] = {kv0, kv1, kv2, kv3};
#pragma unroll
      for (int i = 0; i < 4; i++)
#pragma unroll
        for (int j = 0; j < 4; j++)
          p[i][j] += qv[i].x * kv[j].x + qv[i].y * kv[j].y + qv[i].z * kv[j].z + qv[i].w * kv[j].w;
    }
    __syncthreads();  // all K reads done before w overwrites KsW

    // w + mask + row-sum partials
    const bool diag = (kt == qt);
#pragma unroll
    for (int i = 0; i < 4; i++) {
      int sg = s0 + ty * 4 + i;
      float w0, w1, w2, w3;
      {
        int tg = t0 + tx * 4;
        w0 = p[i][0] * scale * __expf(as_[tx * 4 + 0] - rmv[i]); if (diag && tg + 0 > sg) w0 = 0.f;
        w1 = p[i][1] * scale * __expf(as_[tx * 4 + 1] - rmv[i]); if (diag && tg + 1 > sg) w1 = 0.f;
        w2 = p[i][2] * scale * __expf(as_[tx * 4 + 2] - rmv[i]); if (diag && tg + 2 > sg) w2 = 0.f;
        w3 = p[i][3] * scale * __expf(as_[tx * 4 + 3] - rmv[i]); if (diag && tg + 3 > sg) w3 = 0.f;
      }
      sc_part[i] += w0 + w1 + w2 + w3;
      float4 wv = {w0, w1, w2, w3};
      *(float4*)&KsW[(ty * 4 + i) * 68 + tx * 4] = wv;
    }
    __syncthreads();

    // phase B: accH[i][dd] += sum_c w[row][c] * V[c][tx*8+dd]
    for (int c4 = 0; c4 < 16; c4++) {
      int c = c4 * 4;
      float wq[4][4];
#pragma unroll
      for (int i = 0; i < 4; i++) {
        float4 wr = *(const float4*)&KsW[(ty * 4 + i) * 68 + c];
        wq[i][0] = wr.x; wq[i][1] = wr.y; wq[i][2] = wr.z; wq[i][3] = wr.w;
      }
#pragma unroll
      for (int cj = 0; cj < 4; cj++) {
        float4 v0 = *(const float4*)&Vs[(c + cj) * 132 + tx * 8];
        float4 v1 = *(const float4*)&Vs[(c + cj) * 132 + tx * 8 + 4];
#pragma unroll
        for (int i = 0; i < 4; i++) {
          float wf = wq[i][cj];
          accH[i][0] += wf * v0.x; accH[i][1] += wf * v0.y;
          accH[i][2] += wf * v0.z; accH[i][3] += wf * v0.w;
          accH[i][4] += wf * v1.x; accH[i][5] += wf * v1.y;
          accH[i][6] += wf * v1.z; accH[i][7] += wf * v1.w;
        }
      }
    }
  }
  __syncthreads();  // KsW free for reductions

  // sC reduction -> invn
#pragma unroll
  for (int i = 0; i < 4; i++) KsW[(ty * 4 + i) * 17 + tx] = sc_part[i];
  __syncthreads();
  if (tid < 64) {
    float ssum = 0.f;
#pragma unroll
    for (int t = 0; t < 16; t++) ssum += KsW[tid * 17 + t];
    float nrm = fmaxf(fabsf(ssum), enm_arr[(size_t)bh * S_LEN + s0 + tid]);
    invn[tid] = 1.f / (nrm + 1e-6f);
  }
  __syncthreads();
  // normalize h, LN partials
#pragma unroll
  for (int i = 0; i < 4; i++) {
    float inv = invn[ty * 4 + i];
    float s = 0.f, qq = 0.f;
#pragma unroll
    for (int dd = 0; dd < 8; dd++) {
      float hv = accH[i][dd] * inv;
      accH[i][dd] = hv;
      s += hv; qq += hv * hv;
    }
    KsW[1088 + (ty * 4 + i) * 17 + tx] = s;
    KsW[2176 + (ty * 4 + i) * 17 + tx] = qq;
  }
  __syncthreads();
  if (tid < 64) {
    float s = 0.f, qq = 0.f;
#pragma unroll
    for (int t = 0; t < 16; t++) { s += KsW[1088 + tid * 17 + t]; qq += KsW[2176 + tid * 17 + t]; }
    float mu = s * (1.f / DHEAD);
    float var = qq * (1.f / DHEAD) - mu * mu;
    mu_s[tid] = mu;
    rs_s[tid] = rsqrtf(var + 1e-5f);
  }
  __syncthreads();

  // epilogue: hn*onw + skip*xc, gate by silu(z), store
  float4 ow0 = *(const float4*)(onw + c0 + tx * 8);
  float4 ow1 = *(const float4*)(onw + c0 + tx * 8 + 4);
  float4 sk0 = *(const float4*)(skip + c0 + tx * 8);
  float4 sk1 = *(const float4*)(skip + c0 + tx * 8 + 4);
#pragma unroll
  for (int i = 0; i < 4; i++) {
    int sg = s0 + ty * 4 + i;
    float mu = mu_s[ty * 4 + i], rs = rs_s[ty * 4 + i];
    size_t base = (rowbase + sg) * INNER_D + c0 + tx * 8;
    float4 xc0 = *(const float4*)(xc + base);
    float4 xc1 = *(const float4*)(xc + base + 4);
    float4 z0 = *(const float4*)(z + base);
    float4 z1 = *(const float4*)(z + base + 4);
    float4 o0, o1;
    o0.x = ((accH[i][0] - mu) * rs * ow0.x + sk0.x * xc0.x) * (z0.x / (1.f + __expf(-z0.x)));
    o0.y = ((accH[i][1] - mu) * rs * ow0.y + sk0.y * xc0.y) * (z0.y / (1.f + __expf(-z0.y)));
    o0.z = ((accH[i][2] - mu) * rs * ow0.z + sk0.z * xc0.z) * (z0.z / (1.f + __expf(-z0.z)));
    o0.w = ((accH[i][3] - mu) * rs * ow0.w + sk0.w * xc0.w) * (z0.w / (1.f + __expf(-z0.w)));
    o1.x = ((accH[i][4] - mu) * rs * ow1.x + sk1.x * xc1.x) * (z1.x / (1.f + __expf(-z1.x)));
    o1.y = ((accH[i][5] - mu) * rs * ow1.y + sk1.y * xc1.y) * (z1.y / (1.f + __expf(-z1.y)));
    o1.z = ((accH[i][6] - mu) * rs * ow1.z + sk1.z * xc1.z) * (z1.z / (1.f + __expf(-z1.z)));
    o1.w = ((accH[i][7] - mu) * rs * ow1.w + sk1.w * xc1.w) * (z1.w / (1.f + __expf(-z1.w)));
    *(float4*)(hs + base) = o0;
    *(float4*)(hs + base + 4) = o1;
  }
}

// ---------------- head: out[192,21] = ln96 @ head_W + head_b, store f32 ----------------
__global__ __launch_bounds__(64) void head_kernel(
    const float* __restrict__ ln96, const float* __restrict__ hW, const float* __restrict__ hb,
    float* __restrict__ out)
{
  int row = blockIdx.x;  // 0..191
  int n = threadIdx.x;
  if (n >= 21) return;
  float acc = hb[n];
  const float* xr = ln96 + (size_t)row * E_DIM;
  for (int kk = 0; kk < E_DIM; kk++) acc += xr[kk] * hW[kk * 21 + n];
  out[row * 21 + n] = acc;
}

extern "C" void kernel_launch(void* const* d_in, const int* in_sizes, int n_in,
                              void* d_out, int out_size, void* d_ws, size_t ws_size,
                              hipStream_t stream)
{
  const float* x_enc   = (const float*)d_in[0];
  const float* x_mark  = (const float*)d_in[1];
  const float* emb_W   = (const float*)d_in[4];
  const float* emb_b   = (const float*)d_in[5];
  const float* ln_w    = (const float*)d_in[6];
  const float* up_W    = (const float*)d_in[7];
  const float* conv_W  = (const float*)d_in[8];
  const float* conv_b  = (const float*)d_in[9];
  const float* q_W     = (const float*)d_in[10];
  const float* k_W     = (const float*)d_in[11];
  const float* v_W     = (const float*)d_in[12];
  const float* ig_W    = (const float*)d_in[13];
  const float* ig_b    = (const float*)d_in[14];
  const float* fg_W    = (const float*)d_in[15];
  const float* fg_b    = (const float*)d_in[16];
  const float* skip_w  = (const float*)d_in[17];
  const float* onorm_w = (const float*)d_in[18];
  const float* down_W  = (const float*)d_in[19];
  const float* post_ln = (const float*)d_in[20];
  const float* head_W  = (const float*)d_in[21];
  const float* head_b  = (const float*)d_in[22];

  float* p = (float*)d_ws;
  float* x    = p; p += 1048576;   // 2048*512
  float* xn   = p; p += 1048576;
  float* xm   = p; p += 2097152;   // 2048*1024 (reused as hs after qkv)
  float* z    = p; p += 2097152;
  float* xc   = p; p += 2097152;
  float* qb   = p; p += 2097152;
  float* kb   = p; p += 2097152;
  float* vb   = p; p += 2097152;
  float* igb_ = p; p += 16384;     // 16*1024
  float* fgb_ = p; p += 16384;
  float* ab   = p; p += 16384;
  float* rmb  = p; p += 16384;
  float* enmb = p; p += 16384;
  float* ln96 = p; p += 98304;     // 192*512
  float* hsb  = xm;  // alias: xm dead after qkv_headwise

  embed_kernel<<<2048, 128, 0, stream>>>(x_enc, x_mark, emb_W, emb_b, x);

  for (int L = 0; L < 4; L++) {
    ln_kernel<<<2048, 256, 0, stream>>>(x, ln_w + L * 512, xn);
    gemm_f32<0><<<dim3(32, 32), 256, 0, stream>>>(
        xn, up_W + (size_t)L * 512 * 2048, xm, z, 2048, 2048, 512, 512, 1024, 1024);
    conv_silu_kernel<<<2048, 256, 0, stream>>>(xm, conv_W + L * 4096, conv_b + L * 1024, xc);
    qkv_headwise_kernel<<<2048, 256, 0, stream>>>(
        xc, xm, q_W + L * 4096, k_W + L * 4096, v_W + L * 4096, qb, kb, vb);
    gates_kernel<<<2048, 256, 0, stream>>>(
        qb, kb, vb, ig_W + L * 24576, ig_b + L * 8, fg_W + L * 24576, fg_b + L * 8, igb_, fgb_);
    scan_kernel<<<16, 1024, 0, stream>>>(igb_, fgb_, ab, rmb, enmb);
    attn_tile_kernel<<<dim3(16, 16), 256, 0, stream>>>(
        qb, kb, vb, ab, rmb, enmb, xc, z, skip_w + L * 1024, onorm_w + L * 1024, hsb);
    gemm_f32<1><<<dim3(8, 32), 256, 0, stream>>>(
        hsb, down_W + (size_t)L * 1024 * 512, x, nullptr, 2048, 512, 1024, 1024, 1 << 30, 512);
  }

  ln_final_kernel<<<192, 256, 0, stream>>>(x, post_ln, ln96);
  head_kernel<<<192, 64, 0, stream>>>(ln96, head_W, head_b, (float*)d_out);
}